// Round 12
// baseline (238.018 us; speedup 1.0000x reference)
//
#include <hip/hip_runtime.h>
#include <math.h>

// Problem constants (from reference)
#define NG   1024        // graphs
#define NP   256         // nodes per graph
#define EPG  4096        // edges per graph
#define ETOT 4194304     // total edges
#define FIN  7
#define HD   64
#define KC   50
#define FST  72          // f16 LDS row stride (36w = 4 mod 32)
#define FT2  68          // tail stride (34w = 2 mod 32)
#define TSC  0.00390625f // tail scale 1/256 (exact)
#define TSCI 256.0f      // inverse

// ST (S^T [k][n]) and A-slab: stride 256 halves with XOR swizzle, write and
// read sides use the SAME formula (both-sides-or-neither).
#define SW_ST(k, n)  ((k) * 256 + ((n) ^ (((k) & 7) << 3)))   // half idx
#define SW_AW(r, w)  ((r) * 128 + ((w) ^ (((r) & 7) << 2)))   // word idx
#define SW_AH(r, h)  ((r) * 256 + ((h) ^ (((r) & 7) << 3)))   // half idx

// NOTE (R1-R8): megakernel ladder 321 -> 234.6 total (R8 base: mega 147,
// 1024 thr, 157KB LDS, 1 block/CU, ~59% stall).
// NOTE (R9/R10): bundled micro-opts regressed +10us via codegen/scheduling
// perturbation (busy identical, stall up); R11 restored R8 -> reproduced.
// NOTE (R12, this round): DECISIVE occupancy experiment. R3-R5 showed
// 1024-thr blocks never co-schedule, but couldn't distinguish LDS ceiling
// from the 2048-thread boundary (2x1024 = exact max). This kernel: 512 thr
// (8 waves), 63.3KB LDS (2x = 126.7KB, 2x512 = 1024 thr -- clear of all
// boundaries). Per-wave work x2, barriers ~55: strictly worse at 1/CU,
// strictly better at 2/CU -- time is the unambiguous readout.
// kw_conv restored (global L2-hot weights); t1+P+softmax per 128-row half
// with af kept in regs; SP via 4 chunked K=64 GEMMs (t1T from regs);
// phase 3 = 8 x 32-row slabs.

typedef __attribute__((ext_vector_type(8))) _Float16 v8h;
typedef __attribute__((ext_vector_type(4))) float v4f;

// f16 preconverted weights (rewritten every launch; capture-safe)
__device__ __align__(16) _Float16 g_W1bT[HD * HD];   // W1b^T [d][j]
__device__ __align__(16) _Float16 g_WWT[HD * HD];    // (W1b@Wp)^T [k][j]
__device__ __align__(16) _Float16 g_W2aT[HD * HD];   // W2a^T [d2][d]
__device__ __align__(16) _Float16 g_W2bT[HD * HD];   // W2b^T [j][d2]
__device__ float g_bP[HD];                           // b1b@Wp + bp (pad 0)

// kw_conv: 16 blocks x 256 thr. Transposes + WW fold + bP.
__global__ void kw_conv(const float* __restrict__ W1b, const float* __restrict__ Wp,
                        const float* __restrict__ W2a, const float* __restrict__ W2b,
                        const float* __restrict__ b1b, const float* __restrict__ bp) {
    const int b = blockIdx.x, tid = threadIdx.x;
    {   // transposes: element i of 4096
        int i = b * 256 + tid;
        int d = i >> 6, j = i & 63;
        g_W1bT[i] = (_Float16)W1b[j * HD + d];
        g_W2aT[i] = (_Float16)W2a[j * HD + d];
        g_W2bT[i] = (_Float16)W2b[j * HD + d];
    }
    {   // WW^T[k][j] = sum_d W1b[j][d] Wp[d][k]; rows k>=KC stay 0
        int k = b * 4 + (tid >> 6), j = tid & 63;
        float acc = 0.f;
        if (k < KC) {
            for (int d = 0; d < HD; ++d)
                acc += W1b[j * HD + d] * Wp[d * KC + k];
        }
        g_WWT[k * HD + j] = (_Float16)acc;
    }
    if (tid < 4) {      // bP[k] = sum_d b1b[d] Wp[d][k] + bp[k]
        int k = b * 4 + tid;
        float a = 0.f;
        if (k < KC) {
            for (int d = 0; d < HD; ++d) a += b1b[d] * Wp[d * KC + k];
            a += bp[k];
        }
        g_bP[k] = a;
    }
}

// ws[0]=sumA2, ws[1]=sum S logS, ws[2]=trace(Ap), ws[3]=||G||^2
__global__ void finalize_k(const float* __restrict__ ws, float* __restrict__ out) {
    if (threadIdx.x == 0) {
        float num = ws[0] - 2.f * ws[2] + ws[3];
        float link = sqrtf(fmaxf(num, 0.f)) / 67108864.0f;   // / (B*n*n)
        float ent  = -ws[1] / 262144.0f;                     // / N
        out[2048] = link + ent;
    }
}

// 3-value fused block reduce for 8 waves.
__device__ __forceinline__ void blockReduce3w8(float& a, float& b, float& c,
                                               float* red) {
    __syncthreads();
    #pragma unroll
    for (int o = 32; o > 0; o >>= 1) {
        a += __shfl_down(a, o);
        b += __shfl_down(b, o);
        c += __shfl_down(c, o);
    }
    const int wid = threadIdx.x >> 6;
    if ((threadIdx.x & 63) == 0) {
        red[wid * 3] = a; red[wid * 3 + 1] = b; red[wid * 3 + 2] = c;
    }
    __syncthreads();
    if (threadIdx.x == 0) {
        float ra = 0.f, rb = 0.f, rc = 0.f;
        for (int i = 0; i < 8; ++i) {
            ra += red[i * 3]; rb += red[i * 3 + 1]; rc += red[i * 3 + 2];
        }
        a = ra; b = rb; c = rc;
    }
}

// ---- MEGA: per-graph pipeline, 512 threads (8 waves), ~63.3KB LDS ----------
__launch_bounds__(512, 4)
__global__ void mega(const int* __restrict__ esrc, const int* __restrict__ edst,
                     const float* __restrict__ x,
                     const float* __restrict__ W1a, const float* __restrict__ b1a,
                     const float* __restrict__ b1b,
                     const float* __restrict__ b2a, const float* __restrict__ b2b,
                     const float* __restrict__ Wl,  const float* __restrict__ bl,
                     float* __restrict__ out, float* __restrict__ ws)
{
    __shared__ __align__(16) _Float16 ST[64 * 256];   // 32 KB  S^T [k][n] swz
    __shared__ __align__(16) _Float16 xagg[NP * 8];   // 4 KB   x+agg f16
    __shared__ __align__(16) union {
        struct {                                      // phase 1 (15.4 KB)
            unsigned char ssi[EPG];
            float xt8[NP * 8];
            unsigned int hist[256], cur[256], roff[NP + 1];
        } k1;
        struct {                                      // phase 2 (18.4 KB)
            _Float16 t1b[128 * FST];                  // t1 half [n128][j];
        } k2;                                         // later t1T / SPb [64][72]
        struct {                                      // phase 3 slab (21 KB)
            unsigned int cnt[32 * 128];               // A slab (32 rows) swz
            _Float16 ast[64 * 36];                    // AS^T [c][s32]
        } a;
        struct {                                      // tail (26.1 KB)
            _Float16 Apf_tf[64 * FT2];                // Ap, later t*s
            _Float16 xpT[64 * FT2];
            _Float16 h2f[64 * FT2];
        } b;
    } u;
    __shared__ float cs[64];                          // colsum(S)
    __shared__ float red[24];

    const int g = blockIdx.x, tid = threadIdx.x;
    const int lane = tid & 63, wid = tid >> 6;        // wid 0..7
    const int l15 = lane & 15, quad = lane >> 4, fko = quad * 8;

    // ---- init: zero ST (rows k>=50 must stay 0), hist ----
    for (int i = tid; i < 64 * 128; i += 512) ((unsigned int*)ST)[i] = 0u;
    if (tid < 256) u.k1.hist[tid] = 0u;
    __syncthreads();

    // ---- phase 1a: decode edges (8/thread) + histogram + stage x ----
    unsigned int cellr[8];
    #pragma unroll
    for (int j = 0; j < 8; ++j) {
        int e = tid + j * 512;
        int s = esrc[g * EPG + e] & (NP - 1);
        int d = edst[g * EPG + e] & (NP - 1);
        cellr[j] = (unsigned)((s << 8) | d);
        atomicAdd(&u.k1.hist[d], 1u);
    }
    for (int i = tid; i < NP * 8; i += 512) {
        int n = i >> 3, f = i & 7;
        u.k1.xt8[i] = (f < FIN) ? x[g * NP * FIN + n * FIN + f] : 0.f;
    }
    __syncthreads();

    // ---- phase 1b: exclusive scan (wave 0) ----
    if (wid == 0) {
        unsigned carry = 0;
        for (int c = 0; c < 4; ++c) {
            unsigned v = u.k1.hist[c * 64 + lane];
            unsigned s = v;
            #pragma unroll
            for (int o = 1; o < 64; o <<= 1) {
                unsigned t = __shfl_up(s, o);
                if (lane >= o) s += t;
            }
            unsigned excl = s - v + carry;
            u.k1.roff[c * 64 + lane] = excl;
            u.k1.cur[c * 64 + lane] = excl;
            carry += __shfl(s, 63);
        }
        if (lane == 0) u.k1.roff[NP] = EPG;
    }
    __syncthreads();

    // ---- phase 1c: scatter ----
    #pragma unroll
    for (int j = 0; j < 8; ++j) {
        unsigned c = cellr[j];
        unsigned p2 = atomicAdd(&u.k1.cur[c & 255u], 1u);
        u.k1.ssi[p2] = (unsigned char)(c >> 8);
    }
    __syncthreads();

    // ---- gather agg: 8 lanes per node (64 groups, 4 passes) ----
    {
        const int gi = tid >> 3, f = tid & 7;
        for (int n = gi; n < NP; n += 64) {
            int beg = u.k1.roff[n], end = u.k1.roff[n + 1];
            float a = u.k1.xt8[n * 8 + f];
            for (int e = beg; e < end; ++e)
                a += u.k1.xt8[u.k1.ssi[e] * 8 + f];
            xagg[n * 8 + f] = (_Float16)a;
        }
    }
    __syncthreads();

    // ---- phase 2: t1 + P + softmax, two 128-row halves ----
    // Wave owns rows h*128 + wid*16 .. +16; af fragments kept in regs for SP.
    float entL = 0.f;
    v8h a0, a1, a2, a3;   // t1 af fragments: (half, ks)
    {
        float w1r[FIN];
        #pragma unroll
        for (int f = 0; f < FIN; ++f) w1r[f] = W1a[f * HD + lane];
        float b1r = b1a[lane];

        #pragma unroll
        for (int h = 0; h < 2; ++h) {
            // t1 half: 128 rows, each wave 16 rows (lane = j)
            for (int it = 0; it < 16; ++it) {
                int n = it * 8 + wid;                 // row-local 0..127
                float a = b1r;
                #pragma unroll
                for (int f = 0; f < FIN; ++f)
                    a += (float)xagg[(h * 128 + n) * 8 + f] * w1r[f];
                u.k2.t1b[n * FST + lane] = (_Float16)fmaxf(a, 0.f);
            }
            __syncthreads();

            // load this wave's af fragments (row = wid*16 + l15)
            v8h f0 = *(const v8h*)&u.k2.t1b[(wid * 16 + l15) * FST + fko];
            v8h f1 = *(const v8h*)&u.k2.t1b[(wid * 16 + l15) * FST + 32 + fko];
            if (h == 0) { a0 = f0; a1 = f1; } else { a2 = f0; a3 = f1; }

            // P = t1 @ WW + bP (bf from L2-hot global), softmax in-register
            v4f pa[4];
            #pragma unroll
            for (int c2 = 0; c2 < 4; ++c2) {
                v4f acc = {0.f, 0.f, 0.f, 0.f};
                v8h bf0 = *(const v8h*)&g_WWT[(c2 * 16 + l15) * HD + fko];
                v8h bf1 = *(const v8h*)&g_WWT[(c2 * 16 + l15) * HD + 32 + fko];
                acc = __builtin_amdgcn_mfma_f32_16x16x32_f16(f0, bf0, acc, 0, 0, 0);
                acc = __builtin_amdgcn_mfma_f32_16x16x32_f16(f1, bf1, acc, 0, 0, 0);
                pa[c2] = acc;
            }
            float bv[4]; bool valid[4];
            #pragma unroll
            for (int c2 = 0; c2 < 4; ++c2) {
                int col = c2 * 16 + l15;
                bv[c2] = g_bP[col];
                valid[c2] = col < KC;
            }
            #pragma unroll
            for (int r = 0; r < 4; ++r) {
                float pv[4];
                #pragma unroll
                for (int c2 = 0; c2 < 4; ++c2)
                    pv[c2] = valid[c2] ? (pa[c2][r] + bv[c2]) : -INFINITY;
                float m = fmaxf(fmaxf(pv[0], pv[1]), fmaxf(pv[2], pv[3]));
                #pragma unroll
                for (int o = 8; o > 0; o >>= 1) m = fmaxf(m, __shfl_xor(m, o));
                float e[4], Z = 0.f;
                #pragma unroll
                for (int c2 = 0; c2 < 4; ++c2) {
                    e[c2] = valid[c2] ? __expf(pv[c2] - m) : 0.f;
                    Z += e[c2];
                }
                #pragma unroll
                for (int o = 8; o > 0; o >>= 1) Z += __shfl_xor(Z, o);
                float zi = 1.f / Z, lZ = __logf(Z);
                int row = h * 128 + wid * 16 + quad * 4 + r;
                #pragma unroll
                for (int c2 = 0; c2 < 4; ++c2) {
                    if (valid[c2]) {
                        float s = e[c2] * zi;
                        ST[SW_ST(c2 * 16 + l15, row)] = (_Float16)s;
                        entL += s * (pv[c2] - m);    // sum s log s = this - lZ
                    }
                }
                if (l15 == 0) entL -= lZ;
            }
            __syncthreads();    // t1b rewritten next half / reused as t1T
        }
    }

    // ---- colsum(S) -> cs (reads ST; k = tid>>3, 8 lanes per k) ----
    {
        int k = tid >> 3, q = tid & 7;
        float v = 0.f;
        #pragma unroll
        for (int i = 0; i < 32; ++i) v += (float)ST[SW_ST(k, q * 32 + i)];
        #pragma unroll
        for (int o = 4; o > 0; o >>= 1) v += __shfl_xor(v, o);
        if (q == 0) cs[k] = v;
    }

    // ---- SP = S^T t1: 4 chunks of K=64; t1T written from persistent regs --
    v4f spa[2] = {{0.f, 0.f, 0.f, 0.f}, {0.f, 0.f, 0.f, 0.f}};
    #pragma unroll
    for (int c = 0; c < 4; ++c) {
        if ((wid >> 2) == (c & 1)) {                  // owning 4 waves
            int nl = (wid & 3) * 16 + l15;
            v8h t0 = (c >> 1) ? a2 : a0;
            v8h t1v = (c >> 1) ? a3 : a1;
            #pragma unroll
            for (int k = 0; k < 8; ++k) {
                u.k2.t1b[(fko + k) * FST + nl] = t0[k];
                u.k2.t1b[(32 + fko + k) * FST + nl] = t1v[k];
            }
        }
        __syncthreads();
        #pragma unroll
        for (int tt = 0; tt < 2; ++tt) {
            int t = wid * 2 + tt;
            int mtt = (t >> 2) << 4, ntt = (t & 3) << 4;
            #pragma unroll
            for (int ks = 0; ks < 2; ++ks) {
                v8h af = *(const v8h*)&ST[SW_ST(mtt + l15, c * 64 + ks * 32 + fko)];
                v8h bf = *(const v8h*)&u.k2.t1b[(ntt + l15) * FST + ks * 32 + fko];
                spa[tt] = __builtin_amdgcn_mfma_f32_16x16x32_f16(af, bf, spa[tt], 0, 0, 0);
            }
        }
        __syncthreads();    // t1T rewritten next chunk
    }

    // ---- SP tiles -> SPb (t1b region); xp = SP @ W1b + cs (x) b1b ----
    #pragma unroll
    for (int tt = 0; tt < 2; ++tt) {
        int t = wid * 2 + tt;
        int mtt = (t >> 2) << 4, ntt = (t & 3) << 4;
        #pragma unroll
        for (int r = 0; r < 4; ++r)
            u.k2.t1b[(mtt + quad * 4 + r) * FST + ntt + l15] = (_Float16)spa[tt][r];
    }
    __syncthreads();

    v4f axp[2];
    #pragma unroll
    for (int tt = 0; tt < 2; ++tt) {
        int t = wid * 2 + tt;
        int mtt = (t >> 2) << 4, ntt = (t & 3) << 4;
        float bv = b1b[ntt + l15];
        #pragma unroll
        for (int r = 0; r < 4; ++r) axp[tt][r] = cs[mtt + quad * 4 + r] * bv;
        #pragma unroll
        for (int ks = 0; ks < 2; ++ks) {
            v8h af = *(const v8h*)&u.k2.t1b[(mtt + l15) * FST + ks * 32 + fko];
            v8h bf = *(const v8h*)&g_W1bT[(ntt + l15) * HD + ks * 32 + fko];
            axp[tt] = __builtin_amdgcn_mfma_f32_16x16x32_f16(af, bf, axp[tt], 0, 0, 0);
        }
    }
    __syncthreads();    // SPb (aliases cnt) fully read

    // ---- phase 3: 8 x 32-row dense-A slabs ----
    float sumA2 = 0.f;
    v4f ap[2] = {{0.f, 0.f, 0.f, 0.f}, {0.f, 0.f, 0.f, 0.f}};
    v4f ag[2] = {{0.f, 0.f, 0.f, 0.f}, {0.f, 0.f, 0.f, 0.f}};

    for (int i = tid; i < 32 * 128; i += 512) u.a.cnt[i] = 0u;
    __syncthreads();

    for (int ch = 0; ch < 8; ++ch) {
        int rlo = ch << 5;
        #pragma unroll
        for (int j = 0; j < 8; ++j) {
            unsigned c = cellr[j];
            int sr = (int)(c >> 8) - rlo;
            if ((unsigned)sr < 32u) {
                int d = c & 255u;
                atomicAdd(&u.a.cnt[SW_AW(sr, d >> 1)], (d & 1) ? 0x10000u : 1u);
            }
        }
        __syncthreads();

        // sum(A^2) partial + in-place convert counts -> f16
        for (int i = tid; i < 32 * 128; i += 512) {
            unsigned v = u.a.cnt[i];
            float m0 = (float)(v & 0xffffu), m1 = (float)(v >> 16);
            sumA2 += m0 * m0 + m1 * m1;
            union { unsigned uu; _Float16 hh[2]; } cv;
            cv.hh[0] = (_Float16)m0; cv.hh[1] = (_Float16)m1;
            u.a.cnt[i] = cv.uu;
        }
        __syncthreads();

        const _Float16* Af = (const _Float16*)u.a.cnt;

        // AS_slab = A_slab @ S : [32][64] out, 8 tiles, 1 per wave, K=256
        {
            int mt3 = (wid >> 2) << 4, nt3 = (wid & 3) << 4;
            v4f acc = {0.f, 0.f, 0.f, 0.f};
            #pragma unroll
            for (int ks = 0; ks < 8; ++ks) {
                v8h af = *(const v8h*)&Af[SW_AH(mt3 + l15, ks * 32 + fko)];
                v8h bf = *(const v8h*)&ST[SW_ST(nt3 + l15, ks * 32 + fko)];
                acc = __builtin_amdgcn_mfma_f32_16x16x32_f16(af, bf, acc, 0, 0, 0);
            }
            #pragma unroll
            for (int r = 0; r < 4; ++r)
                u.a.ast[(nt3 + l15) * 36 + mt3 + quad * 4 + r] = (_Float16)acc[r];
        }
        __syncthreads();

        // Ap += S_slab^T @ AS; G += S_slab^T S_slab (K=32); zero cnt for next
        #pragma unroll
        for (int tt = 0; tt < 2; ++tt) {
            int t = wid * 2 + tt;
            int mtt = (t >> 2) << 4, ntt = (t & 3) << 4;
            v8h af = *(const v8h*)&ST[SW_ST(mtt + l15, (ch << 5) + fko)];
            v8h bt = *(const v8h*)&u.a.ast[(ntt + l15) * 36 + fko];
            v8h bs = *(const v8h*)&ST[SW_ST(ntt + l15, (ch << 5) + fko)];
            ap[tt] = __builtin_amdgcn_mfma_f32_16x16x32_f16(af, bt, ap[tt], 0, 0, 0);
            ag[tt] = __builtin_amdgcn_mfma_f32_16x16x32_f16(af, bs, ag[tt], 0, 0, 0);
        }
        if (ch < 7) {   // cnt dead after AS barrier; ast disjoint
            for (int i = tid; i < 32 * 128; i += 512) u.a.cnt[i] = 0u;
        }
        __syncthreads();
    }

    // ---- scalars + f16 Ap / xp^T into tail buffers ----
    float tr = 0.f, g2 = 0.f;
    #pragma unroll
    for (int tt = 0; tt < 2; ++tt) {
        int t = wid * 2 + tt;
        int mtt = (t >> 2) << 4, ntt = (t & 3) << 4;
        int c = ntt + l15;
        #pragma unroll
        for (int r = 0; r < 4; ++r) {
            int k = mtt + quad * 4 + r;
            u.b.Apf_tf[k * FT2 + c] = (_Float16)ap[tt][r];
            u.b.xpT[c * FT2 + k] = (_Float16)axp[tt][r];
            if (k < KC && c < KC) {
                if (k == c) tr += ap[tt][r];
                g2 += ag[tt][r] * ag[tt][r];
            }
        }
    }

    blockReduce3w8(sumA2, tr, g2, red);        // barriers fence u.b writes
    if (tid == 0) {
        atomicAdd(&ws[0], sumA2);
        atomicAdd(&ws[2], tr);
        atomicAdd(&ws[3], g2);
    }
    __syncthreads();

    // ---- tail: h2 = xp + Ap @ xp (scaled 1/256) ----
    #pragma unroll
    for (int tt = 0; tt < 2; ++tt) {
        int t = wid * 2 + tt;
        int mtt = (t >> 2) << 4, ntt = (t & 3) << 4;
        v4f hacc = axp[tt];
        #pragma unroll
        for (int ks = 0; ks < 2; ++ks) {
            v8h af = *(const v8h*)&u.b.Apf_tf[(mtt + l15) * FT2 + ks * 32 + fko];
            v8h bf = *(const v8h*)&u.b.xpT[(ntt + l15) * FT2 + ks * 32 + fko];
            hacc = __builtin_amdgcn_mfma_f32_16x16x32_f16(af, bf, hacc, 0, 0, 0);
        }
        #pragma unroll
        for (int r = 0; r < 4; ++r)
            u.b.h2f[(mtt + quad * 4 + r) * FT2 + ntt + l15] = (_Float16)(hacc[r] * TSC);
    }
    __syncthreads();

    // t*s = relu(h2s @ W2a + s*b2a) -> overwrites Apf
    #pragma unroll
    for (int tt = 0; tt < 2; ++tt) {
        int t = wid * 2 + tt;
        int mtt = (t >> 2) << 4, ntt = (t & 3) << 4;
        float bv = b2a[ntt + l15] * TSC;
        v4f tacc = {bv, bv, bv, bv};
        #pragma unroll
        for (int ks = 0; ks < 2; ++ks) {
            v8h af = *(const v8h*)&u.b.h2f[(mtt + l15) * FT2 + ks * 32 + fko];
            v8h bf = *(const v8h*)&g_W2aT[(ntt + l15) * HD + ks * 32 + fko];
            tacc = __builtin_amdgcn_mfma_f32_16x16x32_f16(af, bf, tacc, 0, 0, 0);
        }
        #pragma unroll
        for (int r = 0; r < 4; ++r)
            u.b.Apf_tf[(mtt + quad * 4 + r) * FT2 + ntt + l15] = (_Float16)fmaxf(tacc[r], 0.f);
    }
    __syncthreads();

    // h3 = (t*s)@W2b * 256 + b2b; fold mean + Wl in fp32
    float l0 = 0.f, l1 = 0.f;
    #pragma unroll
    for (int tt = 0; tt < 2; ++tt) {
        int t = wid * 2 + tt;
        int mtt = (t >> 2) << 4, ntt = (t & 3) << 4;
        v4f oacc = {0.f, 0.f, 0.f, 0.f};
        #pragma unroll
        for (int ks = 0; ks < 2; ++ks) {
            v8h af = *(const v8h*)&u.b.Apf_tf[(mtt + l15) * FT2 + ks * 32 + fko];
            v8h bf = *(const v8h*)&g_W2bT[(ntt + l15) * HD + ks * 32 + fko];
            oacc = __builtin_amdgcn_mfma_f32_16x16x32_f16(af, bf, oacc, 0, 0, 0);
        }
        int j = ntt + l15;
        float bv = b2b[j];
        float wl0 = Wl[j * 2], wl1 = Wl[j * 2 + 1];
        #pragma unroll
        for (int r = 0; r < 4; ++r) {
            int k = mtt + quad * 4 + r;
            if (k < KC) {
                float h3v = oacc[r] * TSCI + bv;
                l0 += h3v * wl0; l1 += h3v * wl1;
            }
        }
    }

    blockReduce3w8(l0, l1, entL, red);
    if (tid == 0) {
        atomicAdd(&ws[1], entL);
        float g0 = bl[0] + l0 * (1.f / KC);
        float g1 = bl[1] + l1 * (1.f / KC);
        float mm = fmaxf(g0, g1);
        float lse = mm + __logf(__expf(g0 - mm) + __expf(g1 - mm));
        out[2 * g]     = g0 - lse;
        out[2 * g + 1] = g1 - lse;
    }
}

extern "C" void kernel_launch(void* const* d_in, const int* in_sizes, int n_in,
                              void* d_out, int out_size, void* d_ws, size_t ws_size,
                              hipStream_t stream) {
    const float* x    = (const float*)d_in[0];
    const float* W1a  = (const float*)d_in[1];
    const float* b1a  = (const float*)d_in[2];
    const float* W1b  = (const float*)d_in[3];
    const float* b1b  = (const float*)d_in[4];
    const float* Wp   = (const float*)d_in[5];
    const float* bp   = (const float*)d_in[6];
    const float* W2a  = (const float*)d_in[7];
    const float* b2a  = (const float*)d_in[8];
    const float* W2b  = (const float*)d_in[9];
    const float* b2b  = (const float*)d_in[10];
    const float* Wl   = (const float*)d_in[11];
    const float* bl   = (const float*)d_in[12];
    const int*   eidx = (const int*)d_in[13];   // [2, E] int32
    float* out = (float*)d_out;
    float* ws  = (float*)d_ws;

    hipMemsetAsync(ws, 0, 4 * sizeof(float), stream);
    kw_conv<<<16, 256, 0, stream>>>(W1b, Wp, W2a, W2b, b1b, bp);
    mega<<<NG, 512, 0, stream>>>(eidx, eidx + ETOT, x,
                                 W1a, b1a, b1b,
                                 b2a, b2b, Wl, bl, out, ws);
    finalize_k<<<1, 64, 0, stream>>>(ws, out);
}